// Round 1
// baseline (8945.338 us; speedup 1.0000x reference)
//
#include <hip/hip_runtime.h>
#include <math.h>

// ---------------------------------------------------------------------------
// LSTM_DNC round 7: kill the h-broadcast redundancy + pack flags.
//  - dnc_seq GEMM waves: 8 K-slices x 2 cell-pairs (was 4q x 4cidx). Each h
//    element now read 2x per block (was 4x): 768KB -> 384KB/block/step.
//  - enc_seq: 8 K-slices, full redundancy removal: 256KB -> 128KB/block/step.
//  - Flags packed at stride 1 (was 32 ints): poll traffic drops ~16x in
//    cacheline count through the coherent fabric.
//  - Machinery, proj_gemm, emits, host logic unchanged from R6.
// ---------------------------------------------------------------------------

#define EPSF 1e-6f

__device__ __forceinline__ float sigmoidf_(float x) { return 1.f / (1.f + expf(-x)); }
__device__ __forceinline__ float softplusf_(float x) {
    return (x > 0.f) ? x + log1pf(expf(-x)) : log1pf(expf(x));
}
__device__ __forceinline__ void stg_coh(float* p, float v) {
    __hip_atomic_store(p, v, __ATOMIC_RELAXED, __HIP_MEMORY_SCOPE_AGENT);
}
__device__ __forceinline__ void st_flag(int* p, int v) {
    __hip_atomic_store(p, v, __ATOMIC_RELAXED, __HIP_MEMORY_SCOPE_AGENT);
}
__device__ __forceinline__ int ld_flag(const int* p) {
    return __hip_atomic_load(p, __ATOMIC_RELAXED, __HIP_MEMORY_SCOPE_AGENT);
}
// packed flags: block i flag at f[i]
__device__ __forceinline__ void poll256(const int* f, int lane, int tgt) {
    for (;;) {
        int a = ld_flag(f + lane);
        int b = ld_flag(f + 64 + lane);
        int c = ld_flag(f + 128 + lane);
        int d = ld_flag(f + 192 + lane);
        if (__all(min(min(a, b), min(c, d)) >= tgt)) break;
        __builtin_amdgcn_s_sleep(2);
    }
}
// poll GEMM block flags (blocks 64..255); one wave
__device__ __forceinline__ void pollg(const int* f, int lane, int tgt) {
    for (;;) {
        int a = ld_flag(f + 64 + lane);
        int b = ld_flag(f + 128 + lane);
        int c = ld_flag(f + 192 + lane);
        if (__all(min(min(a, b), c) >= tgt)) break;
        __builtin_amdgcn_s_sleep(2);
    }
}
// poll xi-cell blocks (192..253); one wave
__device__ __forceinline__ void pollx(const int* f, int lane, int tgt) {
    const int* p = f + 192 + (lane < 62 ? lane : 61);
    while (!__all(ld_flag(p) >= tgt)) __builtin_amdgcn_s_sleep(2);
}
// poll machinery flags (blocks 0..63) at f2[i]; one wave
__device__ __forceinline__ void pollm(const int* f2, int lane, int tgt) {
    while (!__all(ld_flag(f2 + lane) >= tgt)) __builtin_amdgcn_s_sleep(2);
}

// ---------------------------------------------------------------------------
__global__ __launch_bounds__(256) void prep_weights(const float* __restrict__ Whh_c,
                                                    const float* __restrict__ Wih_c,
                                                    float* __restrict__ Wcat) {
    int idx = blockIdx.x * 256 + threadIdx.x;
    if (idx < 3036 * 896) {
        int r = idx / 896, j = idx - r * 896;
        float v;
        if (j < 759) v = Whh_c[r * 759 + j];
        else if (j < 768) v = 0.f;
        else v = Wih_c[r * 640 + 512 + (j - 768)];
        Wcat[idx] = v;
    }
}

// ---------------------------------------------------------------------------
// proj_gemm: OUT^T[j][m] = bias[j] + sum_{k<512} A[arow(m)][k] * W[j][k]
// ---------------------------------------------------------------------------
__global__ __launch_bounds__(256, 2) void proj_gemm(const float* __restrict__ A,
                                                    const float* __restrict__ W,
                                                    const float* __restrict__ bias,
                                                    float* __restrict__ OUT, int Ncols,
                                                    int wstride, int arow_base, int arow_stride_t,
                                                    int arow_stride_b, int arowlen, int Mrows) {
    __shared__ float As[16 * 68];
    __shared__ float Ws[16 * 68];
    const int tid = threadIdx.x;
    const int ntile = blockIdx.x, mtile = blockIdx.y;
    const int tx = tid & 15, ty = tid >> 4;
    const int lr = tid >> 2;
    const int lk = (tid & 3) * 4;
    const size_t arow =
        (size_t)arow_base + (size_t)mtile * arow_stride_t + (size_t)lr * arow_stride_b;
    const float* aptr = A + arow * arowlen + lk;
    const int wn = ntile * 64 + lr;
    const bool wok = (wn < Ncols);
    const float* wptr = W + (size_t)(wok ? wn : 0) * wstride + lk;
    float acc[4][4] = {};
    for (int kt = 0; kt < 512; kt += 16) {
        float4 av = *(const float4*)(aptr + kt);
        float4 w4l = *(const float4*)(wptr + kt);
        if (!wok) w4l = make_float4(0.f, 0.f, 0.f, 0.f);
        __syncthreads();
        As[(lk + 0) * 68 + lr] = av.x;
        As[(lk + 1) * 68 + lr] = av.y;
        As[(lk + 2) * 68 + lr] = av.z;
        As[(lk + 3) * 68 + lr] = av.w;
        Ws[(lk + 0) * 68 + lr] = w4l.x;
        Ws[(lk + 1) * 68 + lr] = w4l.y;
        Ws[(lk + 2) * 68 + lr] = w4l.z;
        Ws[(lk + 3) * 68 + lr] = w4l.w;
        __syncthreads();
#pragma unroll
        for (int k = 0; k < 16; ++k) {
            float4 a4 = *(const float4*)&As[k * 68 + ty * 4];
            float4 w4 = *(const float4*)&Ws[k * 68 + tx * 4];
            acc[0][0] = fmaf(a4.x, w4.x, acc[0][0]);
            acc[0][1] = fmaf(a4.x, w4.y, acc[0][1]);
            acc[0][2] = fmaf(a4.x, w4.z, acc[0][2]);
            acc[0][3] = fmaf(a4.x, w4.w, acc[0][3]);
            acc[1][0] = fmaf(a4.y, w4.x, acc[1][0]);
            acc[1][1] = fmaf(a4.y, w4.y, acc[1][1]);
            acc[1][2] = fmaf(a4.y, w4.z, acc[1][2]);
            acc[1][3] = fmaf(a4.y, w4.w, acc[1][3]);
            acc[2][0] = fmaf(a4.z, w4.x, acc[2][0]);
            acc[2][1] = fmaf(a4.z, w4.y, acc[2][1]);
            acc[2][2] = fmaf(a4.z, w4.z, acc[2][2]);
            acc[2][3] = fmaf(a4.z, w4.w, acc[2][3]);
            acc[3][0] = fmaf(a4.w, w4.x, acc[3][0]);
            acc[3][1] = fmaf(a4.w, w4.y, acc[3][1]);
            acc[3][2] = fmaf(a4.w, w4.z, acc[3][2]);
            acc[3][3] = fmaf(a4.w, w4.w, acc[3][3]);
        }
    }
    const int col0 = ntile * 64 + tx * 4;
    const int row0 = mtile * 64 + ty * 4;
#pragma unroll
    for (int j = 0; j < 4; ++j) {
        int col = col0 + j;
        if (col < Ncols) {
            float bv = bias[col];
            float4 st = make_float4(acc[0][j] + bv, acc[1][j] + bv, acc[2][j] + bv,
                                    acc[3][j] + bv);
            *(float4*)&OUT[(size_t)col * Mrows + row0] = st;
        }
    }
}

// ---------------------------------------------------------------------------
// emit kernels: slot layout [k4*256 + b*4 + k&3] -> row-major outputs (bulk).
// ---------------------------------------------------------------------------
__global__ __launch_bounds__(256) void enc_emit(const float* __restrict__ HSE,
                                                float* __restrict__ ENC, int t0) {
    const int tl = blockIdx.x, bgrp = blockIdx.y;
    const int c4 = threadIdx.x & 127, b = bgrp * 2 + (threadIdx.x >> 7);
    float4 v = *(const float4*)&HSE[(size_t)tl * 32768 + c4 * 256 + b * 4];
    *(float4*)&ENC[((size_t)(t0 + tl) * 64 + b) * 512 + c4 * 4] = v;
}
__global__ __launch_bounds__(256) void out_emit(const float* __restrict__ HS,
                                                float* __restrict__ OUT, int t0) {
    const int tl = blockIdx.x, bgrp = blockIdx.y;
    const int c4 = threadIdx.x & 127, b = bgrp * 2 + (threadIdx.x >> 7);
    float4 v = *(const float4*)&HS[(size_t)tl * 57344 + c4 * 256 + b * 4];
    *(float4*)&OUT[(size_t)b * 131072 + (size_t)(t0 + tl) * 512 + c4 * 4] = v;
}

// ---------------------------------------------------------------------------
// enc_seq: 256 blocks x 512 threads; 8 waves = 8 K-slices (64 floats each).
// Each wave accumulates 2 cells (bk, bk+256) x 4 gates = 8 accs. No h re-read.
// ---------------------------------------------------------------------------
__global__ __launch_bounds__(512, 1) void enc_seq(const float* __restrict__ Whh,
                                                  const float* __restrict__ XPT,
                                                  float* __restrict__ HSE,
                                                  float* __restrict__ CE, int M, int TC,
                                                  int* flags) {
    __shared__ float part[8 * 8 * 64];  // 16 KB
    const int tid = threadIdx.x;
    const int bk = blockIdx.x;
    const int lane = tid & 63;
    const int wv = __builtin_amdgcn_readfirstlane(tid >> 6);
    const int s = wv;  // K-slice 0..7

    const float* wp[8];
#pragma unroll
    for (int cg = 0; cg < 8; ++cg) {
        const int cell = (cg < 4) ? bk : bk + 256;
        const int g = cg & 3;
        wp[cg] = Whh + (size_t)(g * 512 + cell) * 512 + s * 64;
    }
    const bool gw = (wv < 2);
    const int cellg = bk + 256 * (wv & 1);
    float c_reg = 0.f;
    if (gw) c_reg = CE[cellg * 64 + lane];

    for (int tl = 0; tl < TC; ++tl) {
        const float* rslot = HSE + (size_t)((tl + TC - 1) % TC) * 32768;
        float* wslot = HSE + (size_t)tl * 32768;
        float x[4] = {};
        if (gw) {
            const int m = tl * 64 + lane;
#pragma unroll
            for (int g = 0; g < 4; ++g) x[g] = XPT[(size_t)(g * 512 + cellg) * M + m];
        }
        float A[8] = {};
        {
            const float4* __restrict__ hx = (const float4*)rslot + s * 16 * 64;
#pragma unroll 2
            for (int i = 0; i < 16; ++i) {
                float4 hv = hx[i * 64 + lane];
#pragma unroll
                for (int cg = 0; cg < 8; ++cg) {
                    float4 w4 = *(const float4*)(wp[cg] + i * 4);
                    A[cg] = fmaf(hv.x, w4.x, A[cg]);
                    A[cg] = fmaf(hv.y, w4.y, A[cg]);
                    A[cg] = fmaf(hv.z, w4.z, A[cg]);
                    A[cg] = fmaf(hv.w, w4.w, A[cg]);
                }
            }
        }
#pragma unroll
        for (int cg = 0; cg < 8; ++cg) part[(wv * 8 + cg) * 64 + lane] = A[cg];
        __syncthreads();
        if (gw) {
            const int cl = wv & 1;
            float g4[4];
#pragma unroll
            for (int g = 0; g < 4; ++g) {
                float sg = 0.f;
#pragma unroll
                for (int ss = 0; ss < 8; ++ss) sg += part[(ss * 8 + cl * 4 + g) * 64 + lane];
                g4[g] = sg;
            }
            float cc = sigmoidf_(g4[1] + x[1]) * c_reg + sigmoidf_(g4[0] + x[0]) * tanhf(g4[2] + x[2]);
            float hh = sigmoidf_(g4[3] + x[3]) * tanhf(cc);
            c_reg = cc;
            stg_coh(&wslot[(cellg >> 2) * 256 + lane * 4 + (cellg & 3)], hh);
        }
        __syncthreads();  // drains vmcnt before flag
        if (tid == 0) st_flag(flags + bk, tl + 1);
        if (tl + 1 < TC) {
            if (wv == 0) poll256(flags, lane, tl + 1);
            __syncthreads();
        }
    }
    if (gw) CE[cellg * 64 + lane] = c_reg;
}

// ---------------------------------------------------------------------------
// dnc_seq: 256 blocks x 1024 threads.
//  blocks 64..253: GEMM. 16 waves = 8 K-slices x 2 cell-pairs; wave (p,s)
//  accumulates cells base+2p, base+2p+1 x 4 gates over slice s (96 floats of
//  the 768-float h-part; 16 floats of the 128-float rv-part).
//  blocks 0..63: machinery (batch=bk). HS: TC slots of 224 rows x 64 x float4;
//  rows 0..191 = h, rows 192..223 = rv.
// ---------------------------------------------------------------------------
__global__ __launch_bounds__(1024, 4) void dnc_seq(
    const float* __restrict__ Wcat, const float* __restrict__ CPT, float* __restrict__ HS,
    float* __restrict__ CC, float* __restrict__ Mg, float* __restrict__ Ug,
    float* __restrict__ Pg, float* __restrict__ WWg, float* __restrict__ Lg,
    float* __restrict__ WRg, int M, int TC, int* flags) {
    __shared__ float part[16 * 8 * 64];  // 32 KB
    __shared__ float M_l[64 * 33];
    __shared__ float L_l[64 * 65];
    __shared__ float act[256];
    __shared__ float wr_l[256];
    __shared__ float u_l[64], p_l[64], ww_l[64], sM2[64], srt_l[64], asrt_l[64];
    __shared__ float modes_l[12], kss_l[4], scal[4];

    const int tid = threadIdx.x;
    const int bk = blockIdx.x;
    const int lane = tid & 63;
    const int wv = __builtin_amdgcn_readfirstlane(tid >> 6);
    const int s = wv & 7, p = wv >> 3;
    const bool machb = (bk < 64);
    const int base = machb ? 0 : (bk - 64) * 4;
    const int b = bk;
    int* flags2 = flags + 8192;

    // weight streams: 8 (cell-pair x 4 gates) per wave, clamped for tail cells
    const float* wp[8];
    const float* rp[8];
#pragma unroll
    for (int cg = 0; cg < 8; ++cg) {
        int cell = base + p * 2 + (cg >> 2);
        if (cell > 758) cell = 758;
        const int g = cg & 3;
        wp[cg] = Wcat + (size_t)(g * 759 + cell) * 896 + s * 96;
        rp[cg] = Wcat + (size_t)(g * 759 + cell) * 896 + 768 + s * 16;
    }
    // gate-compute waves: wv 0..3 own cell base+wv
    const int cellg = base + (wv & 3);
    const bool gv = !machb && (wv < 4) && (cellg < 759);
    float c_reg = 0.f;
    if (gv) c_reg = CC[cellg * 64 + lane];

    if (machb) {
        if (tid < 256) {
#pragma unroll
            for (int i = 0; i < 8; ++i) {
                int e = tid + 256 * i;
                M_l[(e >> 5) * 33 + (e & 31)] = Mg[b * 2048 + e];
            }
#pragma unroll
            for (int i = 0; i < 16; ++i) {
                int e = tid + 256 * i;
                L_l[(e >> 6) * 65 + (e & 63)] = Lg[b * 4096 + e];
            }
            wr_l[tid] = WRg[b * 256 + tid];
        }
        if (tid < 64) {
            u_l[tid] = Ug[b * 64 + tid];
            p_l[tid] = Pg[b * 64 + tid];
            ww_l[tid] = WWg[b * 64 + tid];
        }
        __syncthreads();
    }

#define ACC768(SLOT)                                                                 \
    {                                                                                \
        const float4* __restrict__ hx = (const float4*)(SLOT) + s * 24 * 64;         \
        _Pragma("unroll 2") for (int i = 0; i < 24; ++i) {                           \
            float4 hv = hx[i * 64 + lane];                                           \
            _Pragma("unroll") for (int cg = 0; cg < 8; ++cg) {                       \
                float4 w4 = *(const float4*)(wp[cg] + i * 4);                        \
                A[cg] = fmaf(hv.x, w4.x, A[cg]);                                     \
                A[cg] = fmaf(hv.y, w4.y, A[cg]);                                     \
                A[cg] = fmaf(hv.z, w4.z, A[cg]);                                     \
                A[cg] = fmaf(hv.w, w4.w, A[cg]);                                     \
            }                                                                        \
        }                                                                            \
    }

    // prologue: CPT(0) preload + acc768 for step 0 from slot TC-1
    float cp[4] = {};
    if (gv) {
#pragma unroll
        for (int g = 0; g < 4; ++g) cp[g] = CPT[(size_t)(g * 759 + cellg) * M + lane];
    }
    float A[8] = {};
    if (!machb) ACC768(HS + (size_t)(TC - 1) * 57344);

    for (int tl = 0; tl < TC; ++tl) {
        const bool last = (tl + 1 == TC);
        const float* rslot = HS + (size_t)((tl + TC - 1) % TC) * 57344;
        float* wslot = HS + (size_t)tl * 57344;
        if (!machb) {
            // ---- finish gates: rv(t-1) part (K=128, slice s = 16 floats) ----
            {
                const float4* __restrict__ hx = (const float4*)rslot + (192 + s * 4) * 64;
#pragma unroll
                for (int i = 0; i < 4; ++i) {
                    float4 hv = hx[i * 64 + lane];
#pragma unroll
                    for (int cg = 0; cg < 8; ++cg) {
                        float4 w4 = *(const float4*)(rp[cg] + i * 4);
                        A[cg] = fmaf(hv.x, w4.x, A[cg]);
                        A[cg] = fmaf(hv.y, w4.y, A[cg]);
                        A[cg] = fmaf(hv.z, w4.z, A[cg]);
                        A[cg] = fmaf(hv.w, w4.w, A[cg]);
                    }
                }
            }
#pragma unroll
            for (int cg = 0; cg < 8; ++cg) part[(wv * 8 + cg) * 64 + lane] = A[cg];
            __syncthreads();
            if (wv < 4) {
                const int cl = wv & 1, pp = wv >> 1;
                float g4[4];
#pragma unroll
                for (int g = 0; g < 4; ++g) {
                    float sg = 0.f;
#pragma unroll
                    for (int ss = 0; ss < 8; ++ss)
                        sg += part[((pp * 8 + ss) * 8 + cl * 4 + g) * 64 + lane];
                    g4[g] = sg;
                }
                float cc =
                    sigmoidf_(g4[1] + cp[1]) * c_reg + sigmoidf_(g4[0] + cp[0]) * tanhf(g4[2] + cp[2]);
                float hh = sigmoidf_(g4[3] + cp[3]) * tanhf(cc);
                c_reg = cc;
                if (gv) stg_coh(&wslot[(bk - 64) * 256 + lane * 4 + wv], hh);
            }
            __syncthreads();  // drains vmcnt for all threads
            if (tid == 0) st_flag(flags + bk, tl + 1);
            if (!last) {
                if (wv == 0) pollg(flags, lane, tl + 1);
                __syncthreads();
                // prefetch CPT(tl+1) — in flight during acc768
                float np[4] = {};
                if (gv) {
                    const int m = (tl + 1) * 64 + lane;
#pragma unroll
                    for (int g = 0; g < 4; ++g) np[g] = CPT[(size_t)(g * 759 + cellg) * M + m];
                }
                // overlap: acc768 for step t+1 from just-published h(t)
#pragma unroll
                for (int cg = 0; cg < 8; ++cg) A[cg] = 0.f;
                ACC768(wslot);
                cp[0] = np[0]; cp[1] = np[1]; cp[2] = np[2]; cp[3] = np[3];
                if (wv == 0) pollm(flags2, lane, tl + 1);
                __syncthreads();
            }
        } else {
            // ---------------- machinery (batch = bk), 7 sync phases ----------------
            if (wv == 0) pollx(flags, lane, tl + 1);
            __syncthreads();
            // P0: activations + pre-write M norms
            if (tid < 247) {
                float v = wslot[(128 + (tid >> 2)) * 256 + b * 4 + (tid & 3)];
                float a;
                if (tid < 128) a = tanhf(v);
                else if (tid < 132) a = softplusf_(v);
                else if (tid < 164) a = tanhf(v);
                else if (tid == 164) a = softplusf_(v);
                else if (tid < 197) a = sigmoidf_(v);
                else if (tid < 229) a = tanhf(v);
                else if (tid < 235) a = sigmoidf_(v);
                else a = v;
                act[tid] = a;
            }
            if (tid < 64) {
                float s2 = 0.f;
                for (int w = 0; w < 32; ++w) {
                    float mm = M_l[tid * 33 + w];
                    s2 = fmaf(mm, mm, s2);
                }
                sM2[tid] = s2;
            }
            __syncthreads();
            // P1: wave0 serial chain (wave-synchronous)
            if (tid < 64) {
                if (tid < 4) {
                    float m0 = act[235 + 3 * tid], m1 = act[236 + 3 * tid],
                          m2 = act[237 + 3 * tid];
                    float mx = fmaxf(m0, fmaxf(m1, m2));
                    float e0 = expf(m0 - mx), e1 = expf(m1 - mx), e2 = expf(m2 - mx);
                    float sm = e0 + e1 + e2;
                    modes_l[3 * tid] = e0 / sm;
                    modes_l[3 * tid + 1] = e1 / sm;
                    modes_l[3 * tid + 2] = e2 / sm;
                    float ks = 0.f;
                    for (int w = 0; w < 32; ++w) {
                        float kk = act[tid * 32 + w];
                        ks = fmaf(kk, kk, ks);
                    }
                    kss_l[tid] = ks;
                }
                if (tid == 4) {
                    float sm = 0.f;
                    for (int w = 0; w < 32; ++w) {
                        float kk = act[132 + w];
                        sm = fmaf(kk, kk, sm);
                    }
                    scal[0] = sm;
                }
                float psi = 1.f;
#pragma unroll
                for (int r = 0; r < 4; ++r) psi *= 1.f - act[229 + r] * wr_l[r * 64 + tid];
                float un = u_l[tid], wwo = ww_l[tid];
                float unew = (un + wwo - un * wwo) * psi;
                u_l[tid] = unew;
                // stable ascending rank (wave-internal LDS)
                int rk = 0;
                for (int m = 0; m < 64; ++m) {
                    float um = u_l[m];
                    rk += (um < unew) || (um == unew && m < tid);
                }
                srt_l[rk] = unew;
                // exclusive prefix product over sorted u
                float v = srt_l[tid];
                float incl = v;
#pragma unroll
                for (int off = 1; off < 64; off <<= 1) {
                    float o = __shfl_up(incl, off);
                    if (tid >= off) incl *= o;
                }
                float excl = __shfl_up(incl, 1);
                if (tid == 0) excl = 1.f;
                asrt_l[tid] = (1.f - v) * excl;
                // content write weights
                float dot = 0.f;
                for (int w = 0; w < 32; ++w) dot = fmaf(act[132 + w], M_l[tid * 33 + w], dot);
                float logit = dot * rsqrtf(sM2[tid] + EPSF) * rsqrtf(scal[0] + EPSF) * act[164];
                float mx = logit;
#pragma unroll
                for (int off = 32; off; off >>= 1) mx = fmaxf(mx, __shfl_xor(mx, off));
                float e = expf(logit - mx);
                float sm = e;
#pragma unroll
                for (int off = 32; off; off >>= 1) sm += __shfl_xor(sm, off);
                float cw = e / sm;
                float a = asrt_l[rk];
                float agv = act[233], wgv = act[234];
                float wn = wgv * (agv * a + (1.f - agv) * cw);
                ww_l[tid] = wn;
                float sw = wn;
#pragma unroll
                for (int off = 32; off; off >>= 1) sw += __shfl_xor(sw, off);
                if (tid == 0) scal[1] = sw;
            }
            __syncthreads();
            // P2: M + L updates (4 waves)
            if (tid < 256) {
#pragma unroll
                for (int i = 0; i < 8; ++i) {
                    int e = tid + 256 * i;
                    int n = e >> 5, w = e & 31;
                    float wwn = ww_l[n];
                    M_l[n * 33 + w] =
                        M_l[n * 33 + w] * (1.f - wwn * act[165 + w]) + wwn * act[197 + w];
                }
#pragma unroll
                for (int i = 0; i < 16; ++i) {
                    int e = tid + 256 * i;
                    int n = e >> 6, m = e & 63;
                    float Lv = L_l[n * 65 + m];
                    Lv = (1.f - ww_l[n] - ww_l[m]) * Lv + ww_l[n] * p_l[m];
                    L_l[n * 65 + m] = (n == m) ? 0.f : Lv;
                }
            }
            __syncthreads();
            // P3: read weights (4 waves, r=wv) + p update (wave0)
            float wrn = 0.f;
            if (tid < 256) {
                const int r = wv;
                const int n = lane;
                if (r == 0) p_l[n] = (1.f - scal[1]) * p_l[n] + ww_l[n];
                float s2 = 0.f;
                for (int w = 0; w < 32; ++w) {
                    float mm = M_l[n * 33 + w];
                    s2 = fmaf(mm, mm, s2);
                }
                float dot = 0.f;
                for (int w = 0; w < 32; ++w) dot = fmaf(act[r * 32 + w], M_l[n * 33 + w], dot);
                float logit = dot * rsqrtf(s2 + EPSF) * rsqrtf(kss_l[r] + EPSF) * act[128 + r];
                float mx = logit;
#pragma unroll
                for (int off = 32; off; off >>= 1) mx = fmaxf(mx, __shfl_xor(mx, off));
                float e = expf(logit - mx);
                float sm = e;
#pragma unroll
                for (int off = 32; off; off >>= 1) sm += __shfl_xor(sm, off);
                float cr = e / sm;
                float fw = 0.f, bw = 0.f;
                for (int m = 0; m < 64; ++m) {
                    float wrm = wr_l[r * 64 + m];
                    fw = fmaf(L_l[n * 65 + m], wrm, fw);
                    bw = fmaf(L_l[m * 65 + n], wrm, bw);
                }
                wrn = modes_l[r * 3] * bw + modes_l[r * 3 + 1] * cr + modes_l[r * 3 + 2] * fw;
            }
            __syncthreads();
            if (tid < 256) wr_l[tid] = wrn;
            __syncthreads();
            // P4: rv + publish
            if (tid < 128) {
                const int r = tid >> 5, w = tid & 31;
                float rv = 0.f;
                for (int n = 0; n < 64; ++n) rv = fmaf(wr_l[r * 64 + n], M_l[n * 33 + w], rv);
                stg_coh(&wslot[(192 + (tid >> 2)) * 256 + b * 4 + (tid & 3)], rv);
            }
            __syncthreads();  // drains vmcnt
            if (tid == 0) st_flag(flags2 + bk, tl + 1);
        }
    }
    if (gv) CC[cellg * 64 + lane] = c_reg;
    if (machb) {
        if (tid < 256) {
#pragma unroll
            for (int i = 0; i < 8; ++i) {
                int e = tid + 256 * i;
                Mg[b * 2048 + e] = M_l[(e >> 5) * 33 + (e & 31)];
            }
#pragma unroll
            for (int i = 0; i < 16; ++i) {
                int e = tid + 256 * i;
                Lg[b * 4096 + e] = L_l[(e >> 6) * 65 + (e & 63)];
            }
            WRg[b * 256 + tid] = wr_l[tid];
        }
        if (tid < 64) {
            Ug[b * 64 + tid] = u_l[tid];
            Pg[b * 64 + tid] = p_l[tid];
            WWg[b * 64 + tid] = ww_l[tid];
        }
    }
}

// ---------------------------------------------------------------------------
extern "C" void kernel_launch(void* const* d_in, const int* in_sizes, int n_in, void* d_out,
                              int out_size, void* d_ws, size_t ws_size, hipStream_t stream) {
    const float* x = (const float*)d_in[0];
    const float* Wih_e = (const float*)d_in[1];
    const float* Whh_e = (const float*)d_in[2];
    const float* b_e = (const float*)d_in[3];
    const float* Wih_c = (const float*)d_in[4];
    const float* Whh_c = (const float*)d_in[5];
    const float* b_c = (const float*)d_in[6];
    float* out = (float*)d_out;
    float* ws = (float*)d_ws;

    int TC = 32;
    while (TC > 2) {
        size_t need =
            ((size_t)11612096 + (size_t)TC * 415488 + (size_t)(512 / TC) * 16384) * 4;
        if (need <= ws_size) break;
        TC >>= 1;
    }
    const int nch = 256 / TC;
    const int M = TC * 64;

    size_t off = 0;
    float* XPT = ws + off; off += (size_t)2048 * M;
    float* CPT = ws + off; off += (size_t)3036 * M;
    float* Wcat = ws + off; off += (size_t)3036 * 896;
    float* ENC = ws + off; off += (size_t)256 * 64 * 512;
    size_t zoff = off;
    float* HSE = ws + off; off += (size_t)TC * 32768;  // enc h slots
    float* CE = ws + off; off += 512 * 64;
    float* HS = ws + off; off += (size_t)TC * 57344;   // dnc h/rv slots
    float* CC = ws + off; off += 759 * 64;
    float* Mg = ws + off; off += 64 * 2048;
    float* Ug = ws + off; off += 64 * 64;
    float* Pg = ws + off; off += 64 * 64;
    float* WWg = ws + off; off += 64 * 64;
    float* Lg = ws + off; off += 64 * 4096;
    float* WRg = ws + off; off += 64 * 256;
    int* BAR = (int*)(ws + off); off += (size_t)2 * nch * 16384;
    size_t zbytes = (off - zoff) * 4;

    hipMemsetAsync(ws + zoff, 0, zbytes, stream);
    prep_weights<<<dim3((3036 * 896 + 255) / 256), dim3(256), 0, stream>>>(Whh_c, Wih_c, Wcat);
    for (int c = 0; c < nch; ++c) {
        proj_gemm<<<dim3(32, TC), dim3(256), 0, stream>>>(x, Wih_e, b_e, XPT, 2048, 512, c * TC,
                                                          1, 256, 512, M);
        enc_seq<<<dim3(256), dim3(512), 0, stream>>>(Whh_e, XPT, HSE, CE, M, TC,
                                                     BAR + (size_t)c * 16384);
        enc_emit<<<dim3(TC, 32), dim3(256), 0, stream>>>(HSE, ENC, c * TC);
    }
    for (int c = 0; c < nch; ++c) {
        proj_gemm<<<dim3(48, TC), dim3(256), 0, stream>>>(ENC, Wih_c, b_c, CPT, 3036, 640,
                                                          c * TC * 64, 64, 1, 512, M);
        dnc_seq<<<dim3(256), dim3(1024), 0, stream>>>(Wcat, CPT, HS, CC, Mg, Ug, Pg, WWg, Lg,
                                                      WRg, M, TC, BAR + (size_t)(nch + c) * 16384);
        out_emit<<<dim3(TC, 32), dim3(256), 0, stream>>>(HS, out, c * TC);
    }
}